// Round 1
// baseline (187.354 us; speedup 1.0000x reference)
//
#include <hip/hip_runtime.h>

typedef __attribute__((ext_vector_type(8))) short bf16x8;
typedef __attribute__((ext_vector_type(4))) float f32x4;

#define CDIM 192
#define NTOK 196
#define LTOT 392
#define BDIM 256

__device__ __forceinline__ ushort f2bf(float f) {
  uint u = __float_as_uint(f);
  u = (u + 0x7FFFu + ((u >> 16) & 1u)) >> 16;
  return (ushort)u;
}
__device__ __forceinline__ float bf2f(ushort h) {
  return __uint_as_float(((uint)h) << 16);
}

// ---------------- prep: fold BN into weights (bf16), build u3/u4/K, zero s ----
__global__ __launch_bounds__(256) void prep_kernel(
    const float* __restrict__ w1, const float* __restrict__ b1, const float* __restrict__ g1,
    const float* __restrict__ be1, const float* __restrict__ m1, const float* __restrict__ v1,
    const float* __restrict__ w2, const float* __restrict__ b2, const float* __restrict__ g2,
    const float* __restrict__ be2, const float* __restrict__ m2, const float* __restrict__ v2,
    const float* __restrict__ w3, const float* __restrict__ b3,
    const float* __restrict__ w4, const float* __restrict__ b4,
    const float* __restrict__ w5, const float* __restrict__ b5,
    ushort* __restrict__ w1b, ushort* __restrict__ w2b,
    float* __restrict__ u3, float* __restrict__ u4, float* __restrict__ cvecs,
    float* __restrict__ Kc, float* __restrict__ s) {
  const int T0 = 36864, T1 = 73728, T2 = 73920, T3 = 74312, T4 = 74696, T5 = 74697, T6 = 123849;
  for (int i = blockIdx.x * blockDim.x + threadIdx.x; i < T6; i += gridDim.x * blockDim.x) {
    if (i < T0) {
      int o = i / CDIM;
      float inv = g1[o] * rsqrtf(v1[o] + 1e-5f);
      w1b[i] = f2bf(w1[i] * inv);
    } else if (i < T1) {
      int j = i - T0; int o = j / CDIM;
      float inv = g2[o] * rsqrtf(v2[o] + 1e-5f);
      w2b[j] = f2bf(w2[j] * inv);
    } else if (i < T2) {
      int ii = i - T1;
      float a = 0.f;
      for (int c = 0; c < CDIM; c++) a += w5[c] * w3[c * CDIM + ii];
      u3[ii] = a;
    } else if (i < T3) {
      int j = i - T2;
      float a = 0.f;
      for (int o = 0; o < 784; o++) a += w5[CDIM + o] * (w4[o * 784 + j] + w4[o * 784 + j + LTOT]);
      u4[j] = a;
    } else if (i < T4) {
      int k = i - T3; int h = k / CDIM, o = k % CDIM;
      const float* bb = h ? b2 : b1; const float* gg = h ? g2 : g1;
      const float* bee = h ? be2 : be1;
      const float* mm = h ? m2 : m1; const float* vv = h ? v2 : v1;
      float inv = gg[o] * rsqrtf(vv[o] + 1e-5f);
      cvecs[k] = (bb[o] - mm[o]) * inv + bee[o];
    } else if (i < T5) {
      float a = b5[0];
      for (int c = 0; c < CDIM; c++) a += w5[c] * b3[c];
      for (int o = 0; o < 784; o++) a += w5[CDIM + o] * b4[o];
      Kc[0] = a;
    } else {
      s[i - T5] = 0.f;
    }
  }
}

// ---------------- phi GEMM: phiT[b,lg,c] = relu(W'·z + c'), fused s partials --
// Block = (b, half). 4 waves, each takes l-tiles of 16 rows; MFMA 16x16x32 bf16.
__global__ __launch_bounds__(256) void phi_kernel(
    const float* __restrict__ x, const float* __restrict__ y,
    const ushort* __restrict__ w1b, const ushort* __restrict__ w2b,
    const float* __restrict__ cvecs, const float* __restrict__ u4,
    ushort* __restrict__ phiT, float* __restrict__ s) {
  const int bh = blockIdx.x, b = bh >> 1, h = bh & 1;
  const float* __restrict__ src = (h ? y : x) + (size_t)b * NTOK * CDIM;
  const ushort* __restrict__ wb = h ? w2b : w1b;
  __shared__ float u4s[NTOK];
  __shared__ float cs[CDIM];
  for (int i = threadIdx.x; i < NTOK; i += BDIM) u4s[i] = u4[h * NTOK + i];
  for (int i = threadIdx.x; i < CDIM; i += BDIM) cs[i] = cvecs[h * CDIM + i];
  __syncthreads();
  const int wid = threadIdx.x >> 6, lane = threadIdx.x & 63;
  const int lrow = lane & 15, kgrp = lane >> 4;
  float sp[12];
#pragma unroll
  for (int i = 0; i < 12; i++) sp[i] = 0.f;

  for (int t = wid; t < 13; t += 4) {           // 13 l-tiles of 16 (196 -> pad 208)
    const int l0 = t * 16;
    const int r = l0 + lrow;
    const bool rv = (r < NTOK);
    bf16x8 afr[6];
#pragma unroll
    for (int kk = 0; kk < 6; kk++) {            // K = 192 = 6 x 32
      float4 f0 = {0.f, 0.f, 0.f, 0.f}, f1 = {0.f, 0.f, 0.f, 0.f};
      if (rv) {
        const float* p = src + (size_t)r * CDIM + kk * 32 + kgrp * 8;
        f0 = *(const float4*)p;
        f1 = *(const float4*)(p + 4);
      }
      bf16x8 a;
      a[0] = (short)f2bf(f0.x); a[1] = (short)f2bf(f0.y);
      a[2] = (short)f2bf(f0.z); a[3] = (short)f2bf(f0.w);
      a[4] = (short)f2bf(f1.x); a[5] = (short)f2bf(f1.y);
      a[6] = (short)f2bf(f1.z); a[7] = (short)f2bf(f1.w);
      afr[kk] = a;
    }
#pragma unroll
    for (int ct = 0; ct < 12; ct++) {           // 192 output channels = 12 x 16
      f32x4 acc = {0.f, 0.f, 0.f, 0.f};
      const int c = ct * 16 + lrow;
#pragma unroll
      for (int kk = 0; kk < 6; kk++) {
        bf16x8 bfr = *(const bf16x8*)(wb + (size_t)c * CDIM + kk * 32 + kgrp * 8);
        acc = __builtin_amdgcn_mfma_f32_16x16x32_bf16(afr[kk], bfr, acc, 0, 0, 0);
      }
      const int lbase = l0 + kgrp * 4;          // C layout: col=lane&15, row=(lane>>4)*4+j
      float spc = 0.f;
#pragma unroll
      for (int j = 0; j < 4; j++) {
        const int l = lbase + j;
        if (l < NTOK) {
          float v = acc[j] + cs[c];
          v = v > 0.f ? v : 0.f;
          phiT[((size_t)b * LTOT + h * NTOK + l) * CDIM + c] = f2bf(v);
          spc += u4s[l] * v;
        }
      }
      sp[ct] += spc;
    }
  }
  // reduce the 4 row-groups (same c) and accumulate s[b,c]
#pragma unroll
  for (int ct = 0; ct < 12; ct++) {
    float v = sp[ct];
    v += __shfl_xor(v, 16);
    v += __shfl_xor(v, 32);
    if (kgrp == 0) atomicAdd(&s[b * CDIM + ct * 16 + lrow], v);
  }
}

// ---------------- W[b,l] = sum_c (u3[c]+s[b,c]) * phi[b,c,l] + K ---------------
__global__ __launch_bounds__(256) void w_kernel(
    const ushort* __restrict__ phiT, const float* __restrict__ s,
    const float* __restrict__ u3, const float* __restrict__ Kc,
    float* __restrict__ W) {
  const int b = blockIdx.x;
  __shared__ float coeff[CDIM];
  for (int i = threadIdx.x; i < CDIM; i += BDIM) coeff[i] = u3[i] + s[b * CDIM + i];
  __syncthreads();
  const int wid = threadIdx.x >> 6, lane = threadIdx.x & 63;
  const float Kv = Kc[0];
  for (int l = wid; l < LTOT; l += 4) {
    const ushort* p = phiT + ((size_t)b * LTOT + l) * CDIM;
    float acc = 0.f;
#pragma unroll
    for (int q = 0; q < 3; q++) {
      const int c = lane + 64 * q;
      acc += coeff[c] * bf2f(p[c]);
    }
#pragma unroll
    for (int off = 32; off > 0; off >>= 1) acc += __shfl_xor(acc, off);
    if (lane == 0) W[b * LTOT + l] = acc + Kv;
  }
}

// ---------------- out[b,c,n] = x[b,n,c]*W[b,n] + y[b,n,c]*W[b,n+196] ----------
// 32x32 LDS transpose tiles; combine x/y/W at load time.
__global__ __launch_bounds__(256) void out_kernel(
    const float* __restrict__ x, const float* __restrict__ y,
    const float* __restrict__ W, float* __restrict__ out) {
  const int bid = blockIdx.x;
  const int b = bid / 42, t = bid % 42;
  const int ct = t / 7, nt = t % 7;        // 6 c-tiles x 7 n-tiles
  __shared__ float tile[32][33];
  const int tx = threadIdx.x & 31, ty = threadIdx.x >> 5;
  const int c0 = ct * 32, n0 = nt * 32;
#pragma unroll
  for (int r2 = 0; r2 < 4; r2++) {
    const int nl = ty + 8 * r2;
    const int n = n0 + nl;
    float v = 0.f;
    if (n < NTOK) {
      const float wx = W[b * LTOT + n];
      const float wy = W[b * LTOT + NTOK + n];
      const size_t xi = ((size_t)b * NTOK + n) * CDIM + c0 + tx;
      v = x[xi] * wx + y[xi] * wy;
    }
    tile[nl][tx] = v;
  }
  __syncthreads();
#pragma unroll
  for (int r2 = 0; r2 < 4; r2++) {
    const int cl = ty + 8 * r2;
    const int n = n0 + tx;
    if (n < NTOK) out[((size_t)b * CDIM + c0 + cl) * NTOK + n] = tile[tx][cl];
  }
}

extern "C" void kernel_launch(void* const* d_in, const int* in_sizes, int n_in,
                              void* d_out, int out_size, void* d_ws, size_t ws_size,
                              hipStream_t stream) {
  const float* x   = (const float*)d_in[0];
  const float* y   = (const float*)d_in[1];
  const float* w1  = (const float*)d_in[2];
  const float* b1  = (const float*)d_in[3];
  const float* g1  = (const float*)d_in[4];
  const float* be1 = (const float*)d_in[5];
  const float* m1  = (const float*)d_in[6];
  const float* v1  = (const float*)d_in[7];
  const float* w2  = (const float*)d_in[8];
  const float* b2  = (const float*)d_in[9];
  const float* g2  = (const float*)d_in[10];
  const float* be2 = (const float*)d_in[11];
  const float* m2  = (const float*)d_in[12];
  const float* v2  = (const float*)d_in[13];
  const float* w3  = (const float*)d_in[14];
  const float* b3  = (const float*)d_in[15];
  const float* w4  = (const float*)d_in[16];
  const float* b4  = (const float*)d_in[17];
  const float* w5  = (const float*)d_in[18];
  const float* b5  = (const float*)d_in[19];
  float* out = (float*)d_out;

  char* ws = (char*)d_ws;
  ushort* w1b  = (ushort*)ws;             // 73728 B
  ushort* w2b  = (ushort*)(ws + 73728);   // 73728 B
  float* fbase = (float*)(ws + 147456);
  float* u3    = fbase;                   // 192
  float* u4    = fbase + 192;             // 392
  float* cvecs = fbase + 584;             // 384 (c1|c2)
  float* Kc    = fbase + 968;             // 1
  float* s     = fbase + 976;             // 256*192 = 49152
  float* W     = fbase + 50176;           // 256*392 = 100352
  // phiT (bf16, 256*392*192 = 38,535,168 B) aliases d_out exactly (same byte count);
  // it is fully written by phi_kernel, consumed by w_kernel, then overwritten by out_kernel.
  ushort* phiT = (ushort*)d_out;

  prep_kernel<<<128, BDIM, 0, stream>>>(w1, b1, g1, be1, m1, v1,
                                        w2, b2, g2, be2, m2, v2,
                                        w3, b3, w4, b4, w5, b5,
                                        w1b, w2b, u3, u4, cvecs, Kc, s);
  phi_kernel<<<512, BDIM, 0, stream>>>(x, y, w1b, w2b, cvecs, u4, phiT, s);
  w_kernel<<<256, BDIM, 0, stream>>>(phiT, s, u3, Kc, W);
  out_kernel<<<256 * 42, BDIM, 0, stream>>>(x, y, W, out);
}

// Round 2
// 135.278 us; speedup vs baseline: 1.3849x; 1.3849x over previous
//
#include <hip/hip_runtime.h>

typedef __attribute__((ext_vector_type(8))) short bf16x8;
typedef __attribute__((ext_vector_type(4))) float f32x4;

#define CDIM 192
#define NTOK 196
#define LTOT 392
#define BDIM 256

__device__ __forceinline__ ushort f2bf(float f) {
  uint u = __float_as_uint(f);
  u = (u + 0x7FFFu + ((u >> 16) & 1u)) >> 16;
  return (ushort)u;
}
__device__ __forceinline__ float bf2f(ushort h) {
  return __uint_as_float(((uint)h) << 16);
}

// ---------------- prep: fold BN into weights (bf16), build u3/u4/K, zero s ----
__global__ __launch_bounds__(256) void prep_kernel(
    const float* __restrict__ w1, const float* __restrict__ b1, const float* __restrict__ g1,
    const float* __restrict__ be1, const float* __restrict__ m1, const float* __restrict__ v1,
    const float* __restrict__ w2, const float* __restrict__ b2, const float* __restrict__ g2,
    const float* __restrict__ be2, const float* __restrict__ m2, const float* __restrict__ v2,
    const float* __restrict__ w3, const float* __restrict__ b3,
    const float* __restrict__ w4, const float* __restrict__ b4,
    const float* __restrict__ w5, const float* __restrict__ b5,
    ushort* __restrict__ w1b, ushort* __restrict__ w2b,
    float* __restrict__ u3, float* __restrict__ u4, float* __restrict__ cvecs,
    float* __restrict__ Kc, float* __restrict__ s) {
  const int T0 = 36864, T1 = 73728, T2 = 73920, T3 = 74312, T4 = 74696, T5 = 74697, T6 = 123849;
  for (int i = blockIdx.x * blockDim.x + threadIdx.x; i < T6; i += gridDim.x * blockDim.x) {
    if (i < T0) {
      int o = i / CDIM;
      float inv = g1[o] * rsqrtf(v1[o] + 1e-5f);
      w1b[i] = f2bf(w1[i] * inv);
    } else if (i < T1) {
      int j = i - T0; int o = j / CDIM;
      float inv = g2[o] * rsqrtf(v2[o] + 1e-5f);
      w2b[j] = f2bf(w2[j] * inv);
    } else if (i < T2) {
      int ii = i - T1;
      float a = 0.f;
      for (int c = 0; c < CDIM; c++) a += w5[c] * w3[c * CDIM + ii];
      u3[ii] = a;
    } else if (i < T3) {
      int j = i - T2;
      float a = 0.f;
      for (int o = 0; o < 784; o++) a += w5[CDIM + o] * (w4[o * 784 + j] + w4[o * 784 + j + LTOT]);
      u4[j] = a;
    } else if (i < T4) {
      int k = i - T3; int h = k / CDIM, o = k % CDIM;
      const float* bb = h ? b2 : b1; const float* gg = h ? g2 : g1;
      const float* bee = h ? be2 : be1;
      const float* mm = h ? m2 : m1; const float* vv = h ? v2 : v1;
      float inv = gg[o] * rsqrtf(vv[o] + 1e-5f);
      cvecs[k] = (bb[o] - mm[o]) * inv + bee[o];
    } else if (i < T5) {
      float a = b5[0];
      for (int c = 0; c < CDIM; c++) a += w5[c] * b3[c];
      for (int o = 0; o < 784; o++) a += w5[CDIM + o] * b4[o];
      Kc[0] = a;
    } else {
      s[i - T5] = 0.f;
    }
  }
}

// ---------------- phi GEMM: phiT[b,lg,c] = relu(W'·z + c'), fused s partials --
// Block = (b, half, lgroup). 4 waves; each wave owns 48 output channels and
// keeps its 18 B-fragments in registers across the whole l-loop.
__global__ __launch_bounds__(256) void phi_kernel(
    const float* __restrict__ x, const float* __restrict__ y,
    const ushort* __restrict__ w1b, const ushort* __restrict__ w2b,
    const float* __restrict__ cvecs, const float* __restrict__ u4,
    ushort* __restrict__ phiT, float* __restrict__ s) {
  const int bid = blockIdx.x;            // 1024 = 512 bh * 2 g
  const int bh = bid >> 1, g = bid & 1;
  const int b = bh >> 1, h = bh & 1;
  const float* __restrict__ src = (h ? y : x) + (size_t)b * NTOK * CDIM;
  const ushort* __restrict__ wb = h ? w2b : w1b;
  __shared__ float u4s[NTOK];
  __shared__ float cs[CDIM];
  for (int i = threadIdx.x; i < NTOK; i += BDIM) u4s[i] = u4[h * NTOK + i];
  for (int i = threadIdx.x; i < CDIM; i += BDIM) cs[i] = cvecs[h * CDIM + i];
  __syncthreads();
  const int wid = threadIdx.x >> 6, lane = threadIdx.x & 63;
  const int lrow = lane & 15, kgrp = lane >> 4;
  const int cbase = wid * 48 + lrow;     // wave wid owns channels [wid*48, wid*48+48)

  bf16x8 bfr[3][6];                      // 72 VGPRs, loaded ONCE
#pragma unroll
  for (int ct = 0; ct < 3; ct++)
#pragma unroll
    for (int kk = 0; kk < 6; kk++)
      bfr[ct][kk] = *(const bf16x8*)(wb + (size_t)(cbase + ct * 16) * CDIM + kk * 32 + kgrp * 8);

  float sp[3] = {0.f, 0.f, 0.f};
  const int t0 = g ? 7 : 0, t1 = g ? 13 : 7;
  for (int t = t0; t < t1; t++) {        // l-tiles of 16 rows
    const int l0 = t * 16;
    const int r = l0 + lrow;
    const bool rv = (r < NTOK);
    bf16x8 afr[6];
#pragma unroll
    for (int kk = 0; kk < 6; kk++) {     // K = 192 = 6 x 32
      float4 f0 = {0.f, 0.f, 0.f, 0.f}, f1 = {0.f, 0.f, 0.f, 0.f};
      if (rv) {
        const float* p = src + (size_t)r * CDIM + kk * 32 + kgrp * 8;
        f0 = *(const float4*)p;
        f1 = *(const float4*)(p + 4);
      }
      bf16x8 a;
      a[0] = (short)f2bf(f0.x); a[1] = (short)f2bf(f0.y);
      a[2] = (short)f2bf(f0.z); a[3] = (short)f2bf(f0.w);
      a[4] = (short)f2bf(f1.x); a[5] = (short)f2bf(f1.y);
      a[6] = (short)f2bf(f1.z); a[7] = (short)f2bf(f1.w);
      afr[kk] = a;
    }
#pragma unroll
    for (int ct = 0; ct < 3; ct++) {
      f32x4 acc = {0.f, 0.f, 0.f, 0.f};
#pragma unroll
      for (int kk = 0; kk < 6; kk++)
        acc = __builtin_amdgcn_mfma_f32_16x16x32_bf16(afr[kk], bfr[ct][kk], acc, 0, 0, 0);
      const int c = cbase + ct * 16;     // C layout: col=lane&15 -> c, row=(lane>>4)*4+j -> l
      const int lbase = l0 + kgrp * 4;
      float spc = 0.f;
#pragma unroll
      for (int j = 0; j < 4; j++) {
        const int l = lbase + j;
        if (l < NTOK) {
          float v = acc[j] + cs[c];
          v = v > 0.f ? v : 0.f;
          phiT[((size_t)b * LTOT + h * NTOK + l) * CDIM + c] = f2bf(v);
          spc += u4s[l] * v;
        }
      }
      sp[ct] += spc;
    }
  }
  // reduce the 4 row-groups (same c) and accumulate s[b,c]
#pragma unroll
  for (int ct = 0; ct < 3; ct++) {
    float v = sp[ct];
    v += __shfl_xor(v, 16);
    v += __shfl_xor(v, 32);
    if (kgrp == 0) atomicAdd(&s[b * CDIM + cbase + ct * 16], v);
  }
}

// ---------------- W[b,l] = sum_c (u3[c]+s[b,c]) * phi[b,c,l] + K ---------------
// 16-lane group per row; ushort4 vector loads (128B coalesced per group).
__global__ __launch_bounds__(256) void w_kernel(
    const ushort* __restrict__ phiT, const float* __restrict__ s,
    const float* __restrict__ u3, const float* __restrict__ Kc,
    float* __restrict__ W) {
  const int b = blockIdx.x;
  __shared__ float coeff[CDIM];
  for (int i = threadIdx.x; i < CDIM; i += BDIM) coeff[i] = u3[i] + s[b * CDIM + i];
  __syncthreads();
  const int wid = threadIdx.x >> 6, lane = threadIdx.x & 63;
  const int lrow = lane & 15, lsub = lane >> 4;
  const float Kv = Kc[0];
  for (int base = wid * 4; base < LTOT; base += 16) {
    const int l = base + lsub;
    float acc = 0.f;
    if (l < LTOT) {
      const ushort* p = phiT + ((size_t)b * LTOT + l) * CDIM;
#pragma unroll
      for (int q = 0; q < 3; q++) {
        const int c = q * 64 + lrow * 4;
        ushort4 v = *(const ushort4*)(p + c);
        acc += coeff[c] * bf2f(v.x) + coeff[c + 1] * bf2f(v.y) +
               coeff[c + 2] * bf2f(v.z) + coeff[c + 3] * bf2f(v.w);
      }
    }
#pragma unroll
    for (int off = 8; off > 0; off >>= 1) acc += __shfl_xor(acc, off);
    if (lrow == 0 && l < LTOT) W[b * LTOT + l] = acc + Kv;
  }
}

// ---------------- out[b,c,n] = x[b,n,c]*W[b,n] + y[b,n,c]*W[b,n+196] ----------
// 32x32 LDS transpose tiles; combine x/y/W at load time.
__global__ __launch_bounds__(256) void out_kernel(
    const float* __restrict__ x, const float* __restrict__ y,
    const float* __restrict__ W, float* __restrict__ out) {
  const int bid = blockIdx.x;
  const int b = bid / 42, t = bid % 42;
  const int ct = t / 7, nt = t % 7;        // 6 c-tiles x 7 n-tiles
  __shared__ float tile[32][33];
  const int tx = threadIdx.x & 31, ty = threadIdx.x >> 5;
  const int c0 = ct * 32, n0 = nt * 32;
#pragma unroll
  for (int r2 = 0; r2 < 4; r2++) {
    const int nl = ty + 8 * r2;
    const int n = n0 + nl;
    float v = 0.f;
    if (n < NTOK) {
      const float wx = W[b * LTOT + n];
      const float wy = W[b * LTOT + NTOK + n];
      const size_t xi = ((size_t)b * NTOK + n) * CDIM + c0 + tx;
      v = x[xi] * wx + y[xi] * wy;
    }
    tile[nl][tx] = v;
  }
  __syncthreads();
#pragma unroll
  for (int r2 = 0; r2 < 4; r2++) {
    const int cl = ty + 8 * r2;
    const int n = n0 + tx;
    if (n < NTOK) out[((size_t)b * CDIM + c0 + cl) * NTOK + n] = tile[tx][cl];
  }
}

extern "C" void kernel_launch(void* const* d_in, const int* in_sizes, int n_in,
                              void* d_out, int out_size, void* d_ws, size_t ws_size,
                              hipStream_t stream) {
  const float* x   = (const float*)d_in[0];
  const float* y   = (const float*)d_in[1];
  const float* w1  = (const float*)d_in[2];
  const float* b1  = (const float*)d_in[3];
  const float* g1  = (const float*)d_in[4];
  const float* be1 = (const float*)d_in[5];
  const float* m1  = (const float*)d_in[6];
  const float* v1  = (const float*)d_in[7];
  const float* w2  = (const float*)d_in[8];
  const float* b2  = (const float*)d_in[9];
  const float* g2  = (const float*)d_in[10];
  const float* be2 = (const float*)d_in[11];
  const float* m2  = (const float*)d_in[12];
  const float* v2  = (const float*)d_in[13];
  const float* w3  = (const float*)d_in[14];
  const float* b3  = (const float*)d_in[15];
  const float* w4  = (const float*)d_in[16];
  const float* b4  = (const float*)d_in[17];
  const float* w5  = (const float*)d_in[18];
  const float* b5  = (const float*)d_in[19];
  float* out = (float*)d_out;

  char* ws = (char*)d_ws;
  ushort* w1b  = (ushort*)ws;             // 73728 B
  ushort* w2b  = (ushort*)(ws + 73728);   // 73728 B
  float* fbase = (float*)(ws + 147456);
  float* u3    = fbase;                   // 192
  float* u4    = fbase + 192;             // 392
  float* cvecs = fbase + 584;             // 384 (c1|c2)
  float* Kc    = fbase + 968;             // 1
  float* s     = fbase + 976;             // 256*192 = 49152
  float* W     = fbase + 50176;           // 256*392 = 100352
  // phiT (bf16, 256*392*192 = 38,535,168 B) aliases d_out exactly (same byte count);
  // fully written by phi_kernel, consumed by w_kernel, then overwritten by out_kernel.
  ushort* phiT = (ushort*)d_out;

  prep_kernel<<<128, BDIM, 0, stream>>>(w1, b1, g1, be1, m1, v1,
                                        w2, b2, g2, be2, m2, v2,
                                        w3, b3, w4, b4, w5, b5,
                                        w1b, w2b, u3, u4, cvecs, Kc, s);
  phi_kernel<<<1024, BDIM, 0, stream>>>(x, y, w1b, w2b, cvecs, u4, phiT, s);
  w_kernel<<<256, BDIM, 0, stream>>>(phiT, s, u3, Kc, W);
  out_kernel<<<256 * 42, BDIM, 0, stream>>>(x, y, W, out);
}

// Round 4
// 110.528 us; speedup vs baseline: 1.6951x; 1.2239x over previous
//
#include <hip/hip_runtime.h>
#include <hip/hip_bf16.h>

typedef __attribute__((ext_vector_type(8))) short bf16x8;
typedef __attribute__((ext_vector_type(4))) float f32x4;

#define CDIM 192
#define NTOK 196
#define LTOT 392
#define BDIM 256
#define NBE 64

__device__ __forceinline__ ushort f2bf(float f) {
  uint u = __float_as_uint(f);
  u = (u + 0x7FFFu + ((u >> 16) & 1u)) >> 16;
  return (ushort)u;
}
__device__ __forceinline__ float bf2f(ushort h) {
  return __uint_as_float(((uint)h) << 16);
}
__device__ __forceinline__ uint pk2(float lo, float hi) {
  __hip_bfloat162 t = __float22bfloat162_rn(float2{lo, hi});
  uint r;
  __builtin_memcpy(&r, &t, 4);
  return r;
}
__device__ __forceinline__ float wave_reduce(float a) {
#pragma unroll
  for (int off = 32; off > 0; off >>= 1) a += __shfl_xor(a, off);
  return a;
}

// ---------------- prep: fold BN (bf16 weights), u3/u4/K via wave-reductions ---
__global__ __launch_bounds__(256) void prep_kernel(
    const float* __restrict__ w1, const float* __restrict__ b1, const float* __restrict__ g1,
    const float* __restrict__ be1, const float* __restrict__ m1, const float* __restrict__ v1,
    const float* __restrict__ w2, const float* __restrict__ b2, const float* __restrict__ g2,
    const float* __restrict__ be2, const float* __restrict__ m2, const float* __restrict__ v2,
    const float* __restrict__ w3, const float* __restrict__ b3,
    const float* __restrict__ w4, const float* __restrict__ b4,
    const float* __restrict__ w5, const float* __restrict__ b5,
    ushort* __restrict__ w1b, ushort* __restrict__ w2b,
    float* __restrict__ u3, float* __restrict__ u4, float* __restrict__ cvecs,
    float* __restrict__ Kc, float* __restrict__ s) {
  const int bid = blockIdx.x;
  const int wid = threadIdx.x >> 6, lane = threadIdx.x & 63;
  if (bid < NBE) {
    // elementwise: w1b | w2b | cvecs | zero s
    for (int i = bid * BDIM + threadIdx.x; i < 123264; i += NBE * BDIM) {
      if (i < 36864) {
        int o = i / CDIM;
        float inv = g1[o] * rsqrtf(v1[o] + 1e-5f);
        w1b[i] = f2bf(w1[i] * inv);
      } else if (i < 73728) {
        int j = i - 36864; int o = j / CDIM;
        float inv = g2[o] * rsqrtf(v2[o] + 1e-5f);
        w2b[j] = f2bf(w2[j] * inv);
      } else if (i < 74112) {
        int k = i - 73728; int h = k / CDIM, o = k % CDIM;
        const float* bb = h ? b2 : b1; const float* gg = h ? g2 : g1;
        const float* bee = h ? be2 : be1;
        const float* mm = h ? m2 : m1; const float* vv = h ? v2 : v1;
        float inv = gg[o] * rsqrtf(vv[o] + 1e-5f);
        cvecs[k] = (bb[o] - mm[o]) * inv + bee[o];
      } else {
        s[i - 74112] = 0.f;
      }
    }
  } else if (bid < NBE + 48) {            // u3: wave per output j
    int j = (bid - NBE) * 4 + wid;
    float a = 0.f;
    for (int c = lane; c < CDIM; c += 64) a += w5[c] * w3[c * CDIM + j];
    a = wave_reduce(a);
    if (lane == 0) u3[j] = a;
  } else if (bid < NBE + 48 + 98) {       // u4: wave per output j
    int j = (bid - NBE - 48) * 4 + wid;
    float a = 0.f;
    for (int o = lane; o < 784; o += 64)
      a += w5[CDIM + o] * (w4[o * 784 + j] + w4[o * 784 + j + LTOT]);
    a = wave_reduce(a);
    if (lane == 0) u4[j] = a;
  } else {                                // Kc: single wave
    if (wid == 0) {
      float a = 0.f;
      for (int i = lane; i < CDIM + 784; i += 64)
        a += (i < CDIM) ? w5[i] * b3[i] : w5[i] * b4[i - CDIM];
      a = wave_reduce(a);
      if (lane == 0) Kc[0] = a + b5[0];
    }
  }
}

// ---------------- phi GEMM: per-kk pipelined, cvt_pk converts, B in registers -
__global__ __launch_bounds__(256) void phi_kernel(
    const float* __restrict__ x, const float* __restrict__ y,
    const ushort* __restrict__ w1b, const ushort* __restrict__ w2b,
    const float* __restrict__ cvecs, const float* __restrict__ u4,
    ushort* __restrict__ phiT, float* __restrict__ s) {
  const int bid = blockIdx.x;            // 2048 = 512 bh * 4 g
  const int bh = bid >> 2, g = bid & 3;
  const int b = bh >> 1, h = bh & 1;
  const float* __restrict__ src = (h ? y : x) + (size_t)b * NTOK * CDIM;
  const ushort* __restrict__ wb = h ? w2b : w1b;
  __shared__ float u4s[208];
  __shared__ float cs[CDIM];
  for (int i = threadIdx.x; i < 208; i += BDIM) u4s[i] = (i < NTOK) ? u4[h * NTOK + i] : 0.f;
  for (int i = threadIdx.x; i < CDIM; i += BDIM) cs[i] = cvecs[h * CDIM + i];
  __syncthreads();
  const int wid = threadIdx.x >> 6, lane = threadIdx.x & 63;
  const int lrow = lane & 15, kgrp = lane >> 4;
  const int cbase = wid * 48 + lrow;     // wave owns channels [wid*48, wid*48+48)

  bf16x8 bfr[3][6];                      // 72 VGPRs, loaded once (L2-hot)
#pragma unroll
  for (int ct = 0; ct < 3; ct++)
#pragma unroll
    for (int kk = 0; kk < 6; kk++)
      bfr[ct][kk] = *(const bf16x8*)(wb + (size_t)(cbase + ct * 16) * CDIM + kk * 32 + kgrp * 8);
  const float csr[3] = {cs[cbase], cs[cbase + 16], cs[cbase + 32]};

  const int t0s[4] = {0, 4, 7, 10}, t1s[4] = {4, 7, 10, 13};
  const int t0 = t0s[g], t1 = t1s[g];
  float sp[3] = {0.f, 0.f, 0.f};

  float4 pfA[6], pfB[6];
  {
    const int r = 16 * t0 + lrow;
    const bool rv = (r < NTOK);
    const float* p = src + (size_t)r * CDIM + kgrp * 8;
#pragma unroll
    for (int kk = 0; kk < 6; kk++) {
      if (rv) { pfA[kk] = *(const float4*)(p + 32 * kk); pfB[kk] = *(const float4*)(p + 32 * kk + 4); }
      else    { pfA[kk] = float4{0,0,0,0}; pfB[kk] = float4{0,0,0,0}; }
    }
  }

  for (int t = t0; t < t1; t++) {
    const int lbase = 16 * t + 4 * kgrp;
    const float4 u4v = *(const float4*)&u4s[lbase];
    const bool hasnext = (t + 1 < t1);
    const int rn = 16 * (t + 1) + lrow;
    const bool rvn = hasnext && (rn < NTOK);
    const float* pn = src + (size_t)rn * CDIM + kgrp * 8;
    f32x4 acc0 = {0.f,0.f,0.f,0.f}, acc1 = {0.f,0.f,0.f,0.f}, acc2 = {0.f,0.f,0.f,0.f};
#pragma unroll
    for (int kk = 0; kk < 6; kk++) {
      uint4 au;
      au.x = pk2(pfA[kk].x, pfA[kk].y); au.y = pk2(pfA[kk].z, pfA[kk].w);
      au.z = pk2(pfB[kk].x, pfB[kk].y); au.w = pk2(pfB[kk].z, pfB[kk].w);
      bf16x8 a;
      __builtin_memcpy(&a, &au, 16);
      if (hasnext) {                     // prefetch next tile's slice kk
        if (rvn) { pfA[kk] = *(const float4*)(pn + 32 * kk); pfB[kk] = *(const float4*)(pn + 32 * kk + 4); }
        else     { pfA[kk] = float4{0,0,0,0}; pfB[kk] = float4{0,0,0,0}; }
      }
      acc0 = __builtin_amdgcn_mfma_f32_16x16x32_bf16(a, bfr[0][kk], acc0, 0, 0, 0);
      acc1 = __builtin_amdgcn_mfma_f32_16x16x32_bf16(a, bfr[1][kk], acc1, 0, 0, 0);
      acc2 = __builtin_amdgcn_mfma_f32_16x16x32_bf16(a, bfr[2][kk], acc2, 0, 0, 0);
    }
    ushort* pT = phiT + ((size_t)b * LTOT + h * NTOK + lbase) * CDIM + cbase;
    auto epi = [&](const f32x4& acc, int ct, float& spc) {
      const float v0 = fmaxf(acc[0] + csr[ct], 0.f);
      const float v1 = fmaxf(acc[1] + csr[ct], 0.f);
      const float v2 = fmaxf(acc[2] + csr[ct], 0.f);
      const float v3 = fmaxf(acc[3] + csr[ct], 0.f);
      const uint p01 = pk2(v0, v1), p23 = pk2(v2, v3);
      ushort* q = pT + ct * 16;
      if (lbase + 0 < NTOK) q[0 * CDIM] = (ushort)p01;
      if (lbase + 1 < NTOK) q[1 * CDIM] = (ushort)(p01 >> 16);
      if (lbase + 2 < NTOK) q[2 * CDIM] = (ushort)p23;
      if (lbase + 3 < NTOK) q[3 * CDIM] = (ushort)(p23 >> 16);
      spc += u4v.x * v0 + u4v.y * v1 + u4v.z * v2 + u4v.w * v3;
    };
    epi(acc0, 0, sp[0]); epi(acc1, 1, sp[1]); epi(acc2, 2, sp[2]);
  }
#pragma unroll
  for (int ct = 0; ct < 3; ct++) {
    float v = sp[ct];
    v += __shfl_xor(v, 16);
    v += __shfl_xor(v, 32);
    if (kgrp == 0) atomicAdd(&s[b * CDIM + cbase + ct * 16], v);
  }
}

// ---------------- W[b,l] = sum_c (u3[c]+s[b,c]) * phi[b,c,l] + K ---------------
__global__ __launch_bounds__(256) void w_kernel(
    const ushort* __restrict__ phiT, const float* __restrict__ s,
    const float* __restrict__ u3, const float* __restrict__ Kc,
    float* __restrict__ W) {
  const int b = blockIdx.x / 7, sl = blockIdx.x % 7;
  __shared__ float coeff[CDIM];
  for (int i = threadIdx.x; i < CDIM; i += BDIM) coeff[i] = u3[i] + s[b * CDIM + i];
  __syncthreads();
  const int wid = threadIdx.x >> 6, lane = threadIdx.x & 63;
  const int lrow = lane & 15, lsub = lane >> 4;
  const float Kv = Kc[0];
  const int start = sl * 56;
  for (int base = start + wid * 4; base < start + 56; base += 16) {
    const int l = base + lsub;
    const ushort* p = phiT + ((size_t)b * LTOT + l) * CDIM;
    float acc = 0.f;
#pragma unroll
    for (int q = 0; q < 3; q++) {
      const int c = q * 64 + lrow * 4;
      ushort4 v = *(const ushort4*)(p + c);
      acc += coeff[c] * bf2f(v.x) + coeff[c + 1] * bf2f(v.y) +
             coeff[c + 2] * bf2f(v.z) + coeff[c + 3] * bf2f(v.w);
    }
#pragma unroll
    for (int off = 8; off > 0; off >>= 1) acc += __shfl_xor(acc, off);
    if (lrow == 0) W[b * LTOT + l] = acc + Kv;
  }
}

// ---------------- out[b,c,n] = x[b,n,c]*W[b,n] + y[b,n,c]*W[b,n+196] ----------
// float4 loads and float4 stores through a 32x33 LDS transpose tile.
__global__ __launch_bounds__(256) void out_kernel(
    const float* __restrict__ x, const float* __restrict__ y,
    const float* __restrict__ W, float* __restrict__ out) {
  const int bid = blockIdx.x;
  const int b = bid / 42, t = bid % 42;
  const int ct = t / 7, nt = t % 7;        // 6 c-tiles x 7 n-tiles
  __shared__ float tile[32][33];
  const int c0 = ct * 32, n0 = nt * 32;
  {
    const int tx4 = threadIdx.x & 7, ny = threadIdx.x >> 3;
    const int n = n0 + ny;
    float4 v = {0.f, 0.f, 0.f, 0.f};
    if (n < NTOK) {
      const float wx = W[b * LTOT + n];
      const float wy = W[b * LTOT + NTOK + n];
      const size_t xi = ((size_t)b * NTOK + n) * CDIM + c0 + 4 * tx4;
      const float4 xv = *(const float4*)&x[xi];
      const float4 yv = *(const float4*)&y[xi];
      v = float4{xv.x * wx + yv.x * wy, xv.y * wx + yv.y * wy,
                 xv.z * wx + yv.z * wy, xv.w * wx + yv.w * wy};
    }
    tile[ny][4 * tx4 + 0] = v.x; tile[ny][4 * tx4 + 1] = v.y;
    tile[ny][4 * tx4 + 2] = v.z; tile[ny][4 * tx4 + 3] = v.w;
  }
  __syncthreads();
  {
    const int cq = threadIdx.x >> 3, nq = threadIdx.x & 7;
    const int nn = n0 + 4 * nq;
    if (nn < NTOK) {
      float4 o;
      o.x = tile[4 * nq + 0][cq]; o.y = tile[4 * nq + 1][cq];
      o.z = tile[4 * nq + 2][cq]; o.w = tile[4 * nq + 3][cq];
      *(float4*)&out[((size_t)b * CDIM + c0 + cq) * NTOK + nn] = o;
    }
  }
}

extern "C" void kernel_launch(void* const* d_in, const int* in_sizes, int n_in,
                              void* d_out, int out_size, void* d_ws, size_t ws_size,
                              hipStream_t stream) {
  const float* x   = (const float*)d_in[0];
  const float* y   = (const float*)d_in[1];
  const float* w1  = (const float*)d_in[2];
  const float* b1  = (const float*)d_in[3];
  const float* g1  = (const float*)d_in[4];
  const float* be1 = (const float*)d_in[5];
  const float* m1  = (const float*)d_in[6];
  const float* v1  = (const float*)d_in[7];
  const float* w2  = (const float*)d_in[8];
  const float* b2  = (const float*)d_in[9];
  const float* g2  = (const float*)d_in[10];
  const float* be2 = (const float*)d_in[11];
  const float* m2  = (const float*)d_in[12];
  const float* v2  = (const float*)d_in[13];
  const float* w3  = (const float*)d_in[14];
  const float* b3  = (const float*)d_in[15];
  const float* w4  = (const float*)d_in[16];
  const float* b4  = (const float*)d_in[17];
  const float* w5  = (const float*)d_in[18];
  const float* b5  = (const float*)d_in[19];
  float* out = (float*)d_out;

  char* ws = (char*)d_ws;
  ushort* w1b  = (ushort*)ws;             // 73728 B
  ushort* w2b  = (ushort*)(ws + 73728);   // 73728 B
  float* fbase = (float*)(ws + 147456);
  float* u3    = fbase;                   // 192
  float* u4    = fbase + 192;             // 392
  float* cvecs = fbase + 584;             // 384 (c1|c2)
  float* Kc    = fbase + 968;             // 1
  float* s     = fbase + 976;             // 256*192 = 49152
  float* W     = fbase + 50176;           // 256*392 = 100352
  // phiT (bf16, 256*392*192 = 38,535,168 B) aliases d_out exactly (same byte count);
  // fully written by phi_kernel, consumed by w_kernel, then overwritten by out_kernel.
  ushort* phiT = (ushort*)d_out;

  prep_kernel<<<211, BDIM, 0, stream>>>(w1, b1, g1, be1, m1, v1,
                                        w2, b2, g2, be2, m2, v2,
                                        w3, b3, w4, b4, w5, b5,
                                        w1b, w2b, u3, u4, cvecs, Kc, s);
  phi_kernel<<<2048, BDIM, 0, stream>>>(x, y, w1b, w2b, cvecs, u4, phiT, s);
  w_kernel<<<256 * 7, BDIM, 0, stream>>>(phiT, s, u3, Kc, W);
  out_kernel<<<256 * 42, BDIM, 0, stream>>>(x, y, W, out);
}

// Round 7
// 68.113 us; speedup vs baseline: 2.7506x; 1.6227x over previous
//
#include <hip/hip_runtime.h>
#include <hip/hip_bf16.h>

typedef __attribute__((ext_vector_type(8))) short bf16x8;
typedef __attribute__((ext_vector_type(4))) float f32x4;

#define CDIM 192
#define NTOK 196
#define LTOT 392
#define BDIM 256
#define NBE 64

__device__ __forceinline__ ushort f2bf(float f) {
  uint u = __float_as_uint(f);
  u = (u + 0x7FFFu + ((u >> 16) & 1u)) >> 16;
  return (ushort)u;
}
__device__ __forceinline__ float bf2f(ushort h) {
  return __uint_as_float(((uint)h) << 16);
}
__device__ __forceinline__ uint pk2(float lo, float hi) {
  __hip_bfloat162 t = __float22bfloat162_rn(float2{lo, hi});
  uint r;
  __builtin_memcpy(&r, &t, 4);
  return r;
}
__device__ __forceinline__ float wave_reduce(float a) {
#pragma unroll
  for (int off = 32; off > 0; off >>= 1) a += __shfl_xor(a, off);
  return a;
}

// ---------------- prep: fold BN (bf16 weights), u3/u4/K via wave-reductions ---
__global__ __launch_bounds__(256) void prep_kernel(
    const float* __restrict__ w1, const float* __restrict__ b1, const float* __restrict__ g1,
    const float* __restrict__ be1, const float* __restrict__ m1, const float* __restrict__ v1,
    const float* __restrict__ w2, const float* __restrict__ b2, const float* __restrict__ g2,
    const float* __restrict__ be2, const float* __restrict__ m2, const float* __restrict__ v2,
    const float* __restrict__ w3, const float* __restrict__ b3,
    const float* __restrict__ w4, const float* __restrict__ b4,
    const float* __restrict__ w5, const float* __restrict__ b5,
    ushort* __restrict__ w1b, ushort* __restrict__ w2b,
    float* __restrict__ u3, float* __restrict__ u4, float* __restrict__ cvecs,
    float* __restrict__ Kc, float* __restrict__ s) {
  const int bid = blockIdx.x;
  const int wid = threadIdx.x >> 6, lane = threadIdx.x & 63;
  if (bid < NBE) {
    for (int i = bid * BDIM + threadIdx.x; i < 123264; i += NBE * BDIM) {
      if (i < 36864) {
        int o = i / CDIM;
        float inv = g1[o] * rsqrtf(v1[o] + 1e-5f);
        w1b[i] = f2bf(w1[i] * inv);
      } else if (i < 73728) {
        int j = i - 36864; int o = j / CDIM;
        float inv = g2[o] * rsqrtf(v2[o] + 1e-5f);
        w2b[j] = f2bf(w2[j] * inv);
      } else if (i < 74112) {
        int k = i - 73728; int h = k / CDIM, o = k % CDIM;
        const float* bb = h ? b2 : b1; const float* gg = h ? g2 : g1;
        const float* bee = h ? be2 : be1;
        const float* mm = h ? m2 : m1; const float* vv = h ? v2 : v1;
        float inv = gg[o] * rsqrtf(vv[o] + 1e-5f);
        cvecs[k] = (bb[o] - mm[o]) * inv + bee[o];
      } else {
        s[i - 74112] = 0.f;
      }
    }
  } else if (bid < NBE + 48) {            // u3: wave per output j
    int j = (bid - NBE) * 4 + wid;
    float a = 0.f;
    for (int c = lane; c < CDIM; c += 64) a += w5[c] * w3[c * CDIM + j];
    a = wave_reduce(a);
    if (lane == 0) u3[j] = a;
  } else if (bid < NBE + 48 + 98) {       // u4: wave per output j
    int j = (bid - NBE - 48) * 4 + wid;
    float a = 0.f;
    for (int o = lane; o < 784; o += 64)
      a += w5[CDIM + o] * (w4[o * 784 + j] + w4[o * 784 + j + LTOT]);
    a = wave_reduce(a);
    if (lane == 0) u4[j] = a;
  } else {                                // Kc: single wave
    if (wid == 0) {
      float a = 0.f;
      for (int i = lane; i < CDIM + 784; i += 64)
        a += (i < CDIM) ? w5[i] * b3[i] : w5[i] * b4[i - CDIM];
      a = wave_reduce(a);
      if (lane == 0) Kc[0] = a + b5[0];
    }
  }
}

// ---------------- phi GEMM v4: coalesced stage -> swizzled LDS -> MFMA --------
// Block = (b,h). 4 rounds of 64 rows; double-buffered LDS A-tile; B in regs.
__global__ __launch_bounds__(256) void phi_kernel(
    const float* __restrict__ x, const float* __restrict__ y,
    const ushort* __restrict__ w1b, const ushort* __restrict__ w2b,
    const float* __restrict__ cvecs, const float* __restrict__ u4,
    ushort* __restrict__ phiT, float* __restrict__ s) {
  const int bh = blockIdx.x, b = bh >> 1, h = bh & 1;
  const float* __restrict__ src = (h ? y : x) + (size_t)b * NTOK * CDIM;
  const ushort* __restrict__ wb = h ? w2b : w1b;
  __shared__ ushort Abuf[2][64 * CDIM];   // 2 x 24KB, XOR-swizzled rows
  __shared__ float u4s[208];
  __shared__ float cs[CDIM];
  const int tid = threadIdx.x;
  for (int i = tid; i < 208; i += BDIM) u4s[i] = (i < NTOK) ? u4[h * NTOK + i] : 0.f;
  for (int i = tid; i < CDIM; i += BDIM) cs[i] = cvecs[h * CDIM + i];

  const int wid = tid >> 6, lane = tid & 63;
  const int lrow = lane & 15, kgrp = lane >> 4;
  const int cbase = wid * 48 + lrow;      // wave owns channels [wid*48, wid*48+48)

  bf16x8 bfr[3][6];                       // B-fragments, loaded once per block
#pragma unroll
  for (int ct = 0; ct < 3; ct++)
#pragma unroll
    for (int kk = 0; kk < 6; kk++)
      bfr[ct][kk] = *(const bf16x8*)(wb + (size_t)(cbase + ct * 16) * CDIM + kk * 32 + kgrp * 8);
  __syncthreads();
  const float csr[3] = {cs[cbase], cs[cbase + 16], cs[cbase + 32]};

  const float4* src4 = (const float4*)src;
  const int NF4 = NTOK * CDIM / 4;        // 9408 float4s total
  float sp[3] = {0.f, 0.f, 0.f};

  float4 pf[12];
#pragma unroll
  for (int p = 0; p < 12; p++) {          // prefetch round 0 (fully valid)
    pf[p] = src4[p * 256 + tid];
  }

  for (int r = 0; r < 4; r++) {
    ushort* Ab = &Abuf[r & 1][0];
    // convert + swizzled ds_write
#pragma unroll
    for (int p = 0; p < 12; p++) {
      const int fi = r * 3072 + p * 256 + tid;
      const int e = fi * 4;
      const int row = e / CDIM;
      const int col = e - row * CDIM;
      const int rl = row & 63;
      uint2 wv;
      if (fi < NF4) { wv.x = pk2(pf[p].x, pf[p].y); wv.y = pk2(pf[p].z, pf[p].w); }
      else          { wv.x = 0u; wv.y = 0u; }
      uint addr = (uint)(rl * (CDIM * 2) + col * 2);
      addr ^= (uint)((rl & 7) << 4);
      *(uint2*)((char*)Ab + addr) = wv;
    }
    // prefetch next round while this round computes
    if (r < 3) {
#pragma unroll
      for (int p = 0; p < 12; p++) {
        const int fi = (r + 1) * 3072 + p * 256 + tid;
        pf[p] = (fi < NF4) ? src4[fi] : float4{0.f, 0.f, 0.f, 0.f};
      }
    }
    __syncthreads();
    // compute: 4 row-tiles of 16, all waves each do all tiles (48 ch per wave)
#pragma unroll
    for (int tt = 0; tt < 4; tt++) {
      const int l0 = r * 64 + tt * 16;
      if (l0 < NTOK) {
        bf16x8 afr[6];
#pragma unroll
        for (int kk = 0; kk < 6; kk++) {
          uint addr = (uint)((tt * 16 + lrow) * (CDIM * 2) + (kk * 32 + kgrp * 8) * 2);
          addr ^= (uint)((lrow & 7) << 4);
          afr[kk] = *(const bf16x8*)((const char*)Ab + addr);
        }
        f32x4 acc0 = {0.f,0.f,0.f,0.f}, acc1 = {0.f,0.f,0.f,0.f}, acc2 = {0.f,0.f,0.f,0.f};
#pragma unroll
        for (int kk = 0; kk < 6; kk++) {
          acc0 = __builtin_amdgcn_mfma_f32_16x16x32_bf16(afr[kk], bfr[0][kk], acc0, 0, 0, 0);
          acc1 = __builtin_amdgcn_mfma_f32_16x16x32_bf16(afr[kk], bfr[1][kk], acc1, 0, 0, 0);
          acc2 = __builtin_amdgcn_mfma_f32_16x16x32_bf16(afr[kk], bfr[2][kk], acc2, 0, 0, 0);
        }
        const int lbase = l0 + 4 * kgrp;
        const float4 u4v = *(const float4*)&u4s[lbase];
        ushort* pT = phiT + ((size_t)b * LTOT + h * NTOK + lbase) * CDIM + cbase;
        auto epi = [&](const f32x4& acc, int ct, float& spc) {
          const float v0 = fmaxf(acc[0] + csr[ct], 0.f);
          const float v1 = fmaxf(acc[1] + csr[ct], 0.f);
          const float v2 = fmaxf(acc[2] + csr[ct], 0.f);
          const float v3 = fmaxf(acc[3] + csr[ct], 0.f);
          const uint p01 = pk2(v0, v1), p23 = pk2(v2, v3);
          ushort* q = pT + ct * 16;
          if (lbase + 0 < NTOK) q[0 * CDIM] = (ushort)p01;
          if (lbase + 1 < NTOK) q[1 * CDIM] = (ushort)(p01 >> 16);
          if (lbase + 2 < NTOK) q[2 * CDIM] = (ushort)p23;
          if (lbase + 3 < NTOK) q[3 * CDIM] = (ushort)(p23 >> 16);
          spc += u4v.x * v0 + u4v.y * v1 + u4v.z * v2 + u4v.w * v3;
        };
        epi(acc0, 0, sp[0]); epi(acc1, 1, sp[1]); epi(acc2, 2, sp[2]);
      }
    }
    // next round writes the other buffer; round r+1's barrier orders
    // write(r+2) against compute(r).
  }
#pragma unroll
  for (int ct = 0; ct < 3; ct++) {
    float v = sp[ct];
    v += __shfl_xor(v, 16);
    v += __shfl_xor(v, 32);
    if (kgrp == 0) atomicAdd(&s[b * CDIM + cbase + ct * 16], v);
  }
}

// ---------------- W[b,l] = sum_c (u3[c]+s[b,c]) * phi[b,c,l] + K ---------------
__global__ __launch_bounds__(256) void w_kernel(
    const ushort* __restrict__ phiT, const float* __restrict__ s,
    const float* __restrict__ u3, const float* __restrict__ Kc,
    float* __restrict__ W) {
  const int b = blockIdx.x / 7, sl = blockIdx.x % 7;
  __shared__ float coeff[CDIM];
  for (int i = threadIdx.x; i < CDIM; i += BDIM) coeff[i] = u3[i] + s[b * CDIM + i];
  __syncthreads();
  const int wid = threadIdx.x >> 6, lane = threadIdx.x & 63;
  const int lrow = lane & 15, lsub = lane >> 4;
  const float Kv = Kc[0];
  const int start = sl * 56;
  for (int base = start + wid * 4; base < start + 56; base += 16) {
    const int l = base + lsub;
    const ushort* p = phiT + ((size_t)b * LTOT + l) * CDIM;
    float acc = 0.f;
#pragma unroll
    for (int q = 0; q < 3; q++) {
      const int c = q * 64 + lrow * 4;
      ushort4 v = *(const ushort4*)(p + c);
      acc += coeff[c] * bf2f(v.x) + coeff[c + 1] * bf2f(v.y) +
             coeff[c + 2] * bf2f(v.z) + coeff[c + 3] * bf2f(v.w);
    }
#pragma unroll
    for (int off = 8; off > 0; off >>= 1) acc += __shfl_xor(acc, off);
    if (lrow == 0) W[b * LTOT + l] = acc + Kv;
  }
}

// ---------------- out[b,c,n] = x[b,n,c]*W[b,n] + y[b,n,c]*W[b,n+196] ----------
__global__ __launch_bounds__(256) void out_kernel(
    const float* __restrict__ x, const float* __restrict__ y,
    const float* __restrict__ W, float* __restrict__ out) {
  const int bid = blockIdx.x;
  const int b = bid / 42, t = bid % 42;
  const int ct = t / 7, nt = t % 7;        // 6 c-tiles x 7 n-tiles
  __shared__ float tile[32][33];
  const int c0 = ct * 32, n0 = nt * 32;
  {
    const int tx4 = threadIdx.x & 7, ny = threadIdx.x >> 3;
    const int n = n0 + ny;
    float4 v = {0.f, 0.f, 0.f, 0.f};
    if (n < NTOK) {
      const float wx = W[b * LTOT + n];
      const float wy = W[b * LTOT + NTOK + n];
      const size_t xi = ((size_t)b * NTOK + n) * CDIM + c0 + 4 * tx4;
      const float4 xv = *(const float4*)&x[xi];
      const float4 yv = *(const float4*)&y[xi];
      v = float4{xv.x * wx + yv.x * wy, xv.y * wx + yv.y * wy,
                 xv.z * wx + yv.z * wy, xv.w * wx + yv.w * wy};
    }
    tile[ny][4 * tx4 + 0] = v.x; tile[ny][4 * tx4 + 1] = v.y;
    tile[ny][4 * tx4 + 2] = v.z; tile[ny][4 * tx4 + 3] = v.w;
  }
  __syncthreads();
  {
    const int cq = threadIdx.x >> 3, nq = threadIdx.x & 7;
    const int nn = n0 + 4 * nq;
    if (nn < NTOK) {
      float4 o;
      o.x = tile[4 * nq + 0][cq]; o.y = tile[4 * nq + 1][cq];
      o.z = tile[4 * nq + 2][cq]; o.w = tile[4 * nq + 3][cq];
      *(float4*)&out[((size_t)b * CDIM + c0 + cq) * NTOK + nn] = o;
    }
  }
}

extern "C" void kernel_launch(void* const* d_in, const int* in_sizes, int n_in,
                              void* d_out, int out_size, void* d_ws, size_t ws_size,
                              hipStream_t stream) {
  const float* x   = (const float*)d_in[0];
  const float* y   = (const float*)d_in[1];
  const float* w1  = (const float*)d_in[2];
  const float* b1  = (const float*)d_in[3];
  const float* g1  = (const float*)d_in[4];
  const float* be1 = (const float*)d_in[5];
  const float* m1  = (const float*)d_in[6];
  const float* v1  = (const float*)d_in[7];
  const float* w2  = (const float*)d_in[8];
  const float* b2  = (const float*)d_in[9];
  const float* g2  = (const float*)d_in[10];
  const float* be2 = (const float*)d_in[11];
  const float* m2  = (const float*)d_in[12];
  const float* v2  = (const float*)d_in[13];
  const float* w3  = (const float*)d_in[14];
  const float* b3  = (const float*)d_in[15];
  const float* w4  = (const float*)d_in[16];
  const float* b4  = (const float*)d_in[17];
  const float* w5  = (const float*)d_in[18];
  const float* b5  = (const float*)d_in[19];
  float* out = (float*)d_out;

  char* ws = (char*)d_ws;
  ushort* w1b  = (ushort*)ws;             // 73728 B
  ushort* w2b  = (ushort*)(ws + 73728);   // 73728 B
  float* fbase = (float*)(ws + 147456);
  float* u3    = fbase;                   // 192
  float* u4    = fbase + 192;             // 392
  float* cvecs = fbase + 584;             // 384 (c1|c2)
  float* Kc    = fbase + 968;             // 1
  float* s     = fbase + 976;             // 256*192 = 49152
  float* W     = fbase + 50176;           // 256*392 = 100352
  // phiT (bf16) aliases d_out exactly (same byte count); fully written by
  // phi_kernel, consumed by w_kernel, then overwritten by out_kernel.
  ushort* phiT = (ushort*)d_out;

  prep_kernel<<<211, BDIM, 0, stream>>>(w1, b1, g1, be1, m1, v1,
                                        w2, b2, g2, be2, m2, v2,
                                        w3, b3, w4, b4, w5, b5,
                                        w1b, w2b, u3, u4, cvecs, Kc, s);
  phi_kernel<<<512, BDIM, 0, stream>>>(x, y, w1b, w2b, cvecs, u4, phiT, s);
  w_kernel<<<256 * 7, BDIM, 0, stream>>>(phiT, s, u3, Kc, W);
  out_kernel<<<256 * 42, BDIM, 0, stream>>>(x, y, W, out);
}